// Round 1
// baseline (2982.757 us; speedup 1.0000x reference)
//
#include <hip/hip_runtime.h>
#include <cstdint>
#include <cstddef>

typedef _Float16 f16;
typedef __attribute__((ext_vector_type(4))) _Float16 f16x4;
typedef __attribute__((ext_vector_type(8))) _Float16 f16x8;
typedef __attribute__((ext_vector_type(4))) float f32x4;
typedef uint32_t u32;
typedef uint16_t u16;
typedef unsigned long long u64;

#define N_NODES 8192
#define T_STEPS 32
#define H_DIM   256
#define N_EDGES 1024
#define NNZ_    65536

// ------------------------------------------------------------------
// counting sort of nodes by length, descending. Also emits M_t = #{len>t}.
__global__ void k_sort(const int* __restrict__ len, int* __restrict__ order,
                       int* __restrict__ len_s, int* __restrict__ Mts) {
  __shared__ int hist[33];
  __shared__ int cur[33];
  int tid = threadIdx.x;
  if (tid < 33) hist[tid] = 0;
  __syncthreads();
  for (int i = tid; i < N_NODES; i += 256) {
    int l = len[i]; l = l < 0 ? 0 : (l > 32 ? 32 : l);
    atomicAdd(&hist[l], 1);
  }
  __syncthreads();
  if (tid == 0) {
    int acc = 0;
    for (int l = 32; l >= 0; --l) { cur[l] = acc; acc += hist[l]; }
    for (int t = 0; t < 32; ++t) Mts[t] = cur[t];  // cur[t] = #{len > t}
  }
  __syncthreads();
  for (int i = tid; i < N_NODES; i += 256) {
    int l = len[i]; l = l < 0 ? 0 : (l > 32 ? 32 : l);
    int pos = atomicAdd(&cur[l], 1);
    order[pos] = i; len_s[pos] = l;
  }
}

__global__ void k_w16(const float* __restrict__ wih, const float* __restrict__ whh,
                      f16* __restrict__ wih16, f16* __restrict__ whh16) {
  int i = blockIdx.x * 256 + threadIdx.x;
  if (i < 768 * 256) { wih16[i] = (f16)wih[i]; whh16[i] = (f16)whh[i]; }
}

__global__ void k_hinit(const float* __restrict__ h0, float* __restrict__ h) {
  int i = blockIdx.x * 256 + threadIdx.x;   // N_NODES*H_DIM threads
  h[i] = h0[i & (H_DIM - 1)];
}

__global__ void k_hist(const int* __restrict__ he, u32* __restrict__ hd, u32* __restrict__ hb) {
  int i = blockIdx.x * 256 + threadIdx.x;
  if (i < NNZ_) {
    atomicAdd(&hd[he[i]], 1u);
    atomicAdd(&hb[he[NNZ_ + i]], 1u);
  }
}

__global__ void k_inv(const u32* __restrict__ hd, const u32* __restrict__ hb,
                      float* __restrict__ dinv, float* __restrict__ binv) {
  int i = blockIdx.x * 256 + threadIdx.x;
  if (i < N_NODES) dinv[i] = hd[i] ? 1.0f / (float)hd[i] : 0.0f;
  if (i < N_EDGES) binv[i] = hb[i] ? 1.0f / (float)hb[i] : 0.0f;
}

// ------------------------------------------------------------------
// One GRU time step, fused input+recurrent GEMM + cell epilogue.
// Sorted node space; h split hi/lo (f16x2) so per-step quantization does not accumulate.
// Tile: BM=64 nodes x BN=64 gate-dims, K=256, 4 waves (each 64x16).
__global__ __launch_bounds__(256)
void k_gru_step(const float* __restrict__ x, const float* __restrict__ hprev,
                float* __restrict__ hnext, float* __restrict__ last,
                const f16* __restrict__ wih, const f16* __restrict__ whh,
                const float* __restrict__ bih, const float* __restrict__ bhh,
                const int* __restrict__ order, const int* __restrict__ len_s,
                const int* __restrict__ Mts, int t) {
  int Mt = Mts[t];
  int m0 = blockIdx.y * 64;
  if (m0 >= Mt) return;
  int j0 = blockIdx.x * 64;
  __shared__ f16 Ax[64 * 40], Ahh[64 * 40], Ahl[64 * 40];
  __shared__ f16 Bw[6][64 * 40];   // 0..2: W_ih r,z,n  3..5: W_hh r,z,n
  __shared__ int sOrd[64], sLen[64];
  int tid = threadIdx.x;
  if (tid < 64) {
    int g = m0 + tid; if (g > Mt - 1) g = Mt - 1;
    sOrd[tid] = order[g]; sLen[tid] = len_s[g];
  }
  __syncthreads();

  int lane = tid & 63, wid = tid >> 6;
  int quad = lane >> 4, mr = lane & 15;
  f32x4 accR[4] = {}, accZ[4] = {}, accXN[4] = {}, accHN[4] = {};

  for (int kt = 0; kt < 8; ++kt) {
    int k0 = kt * 32;
#pragma unroll
    for (int i = 0; i < 2; ++i) {
      int q = tid + 256 * i;            // 512 float4: 64 rows x 8 f4
      int row = q >> 3, kc = (q & 7) << 2;
      int rclamp = m0 + row; if (rclamp > Mt - 1) rclamp = Mt - 1;
      const float4 vx = *reinterpret_cast<const float4*>(
          &x[(size_t)sOrd[row] * (T_STEPS * H_DIM) + (size_t)t * H_DIM + k0 + kc]);
      f16x4 hx;
      hx[0] = (f16)vx.x; hx[1] = (f16)vx.y; hx[2] = (f16)vx.z; hx[3] = (f16)vx.w;
      *reinterpret_cast<f16x4*>(&Ax[row * 40 + kc]) = hx;
      const float4 vh = *reinterpret_cast<const float4*>(
          &hprev[(size_t)rclamp * H_DIM + k0 + kc]);
      f16 h0_ = (f16)vh.x, h1_ = (f16)vh.y, h2_ = (f16)vh.z, h3_ = (f16)vh.w;
      f16x4 hh, hl;
      hh[0] = h0_; hh[1] = h1_; hh[2] = h2_; hh[3] = h3_;
      hl[0] = (f16)(vh.x - (float)h0_); hl[1] = (f16)(vh.y - (float)h1_);
      hl[2] = (f16)(vh.z - (float)h2_); hl[3] = (f16)(vh.w - (float)h3_);
      *reinterpret_cast<f16x4*>(&Ahh[row * 40 + kc]) = hh;
      *reinterpret_cast<f16x4*>(&Ahl[row * 40 + kc]) = hl;
    }
#pragma unroll
    for (int i = 0; i < 6; ++i) {
      int c = tid + 256 * i;            // 1536 chunks of 8 f16
      int mat = c >> 8, cc = c & 255;
      int row = cc >> 2, kc = (cc & 3) << 3;
      const f16* src = (mat < 3) ? wih : whh;
      int gate = (mat < 3) ? mat : mat - 3;
      f16x8 v = *reinterpret_cast<const f16x8*>(
          &src[(size_t)(gate * 256 + j0 + row) * 256 + k0 + kc]);
      *reinterpret_cast<f16x8*>(&Bw[mat][row * 40 + kc]) = v;
    }
    __syncthreads();
    f16x8 bfr[6];
#pragma unroll
    for (int mmt = 0; mmt < 6; ++mmt)
      bfr[mmt] = *reinterpret_cast<const f16x8*>(&Bw[mmt][(wid * 16 + mr) * 40 + quad * 8]);
#pragma unroll
    for (int im = 0; im < 4; ++im) {
      f16x8 ax = *reinterpret_cast<const f16x8*>(&Ax[(im * 16 + mr) * 40 + quad * 8]);
      f16x8 ah = *reinterpret_cast<const f16x8*>(&Ahh[(im * 16 + mr) * 40 + quad * 8]);
      f16x8 al = *reinterpret_cast<const f16x8*>(&Ahl[(im * 16 + mr) * 40 + quad * 8]);
      accR[im]  = __builtin_amdgcn_mfma_f32_16x16x32_f16(ax, bfr[0], accR[im], 0, 0, 0);
      accR[im]  = __builtin_amdgcn_mfma_f32_16x16x32_f16(ah, bfr[3], accR[im], 0, 0, 0);
      accR[im]  = __builtin_amdgcn_mfma_f32_16x16x32_f16(al, bfr[3], accR[im], 0, 0, 0);
      accZ[im]  = __builtin_amdgcn_mfma_f32_16x16x32_f16(ax, bfr[1], accZ[im], 0, 0, 0);
      accZ[im]  = __builtin_amdgcn_mfma_f32_16x16x32_f16(ah, bfr[4], accZ[im], 0, 0, 0);
      accZ[im]  = __builtin_amdgcn_mfma_f32_16x16x32_f16(al, bfr[4], accZ[im], 0, 0, 0);
      accXN[im] = __builtin_amdgcn_mfma_f32_16x16x32_f16(ax, bfr[2], accXN[im], 0, 0, 0);
      accHN[im] = __builtin_amdgcn_mfma_f32_16x16x32_f16(ah, bfr[5], accHN[im], 0, 0, 0);
      accHN[im] = __builtin_amdgcn_mfma_f32_16x16x32_f16(al, bfr[5], accHN[im], 0, 0, 0);
    }
    __syncthreads();
  }
  // epilogue: GRU cell. C/D layout: col=lane&15 (j), row=quad*4+reg (m).
  int j = j0 + wid * 16 + mr;
  float bir = bih[j], biz = bih[256 + j], bin_ = bih[512 + j];
  float bhr = bhh[j], bhz = bhh[256 + j], bhn = bhh[512 + j];
#pragma unroll
  for (int im = 0; im < 4; ++im) {
#pragma unroll
    for (int r = 0; r < 4; ++r) {
      int mloc = im * 16 + quad * 4 + r;
      int m = m0 + mloc;
      if (m < Mt) {
        float rg = 1.0f / (1.0f + expf(-(accR[im][r] + bir + bhr)));
        float zg = 1.0f / (1.0f + expf(-(accZ[im][r] + biz + bhz)));
        float ng = tanhf(accXN[im][r] + bin_ + rg * (accHN[im][r] + bhn));
        float hp = hprev[(size_t)m * H_DIM + j];
        float hv = (1.0f - zg) * ng + zg * hp;
        hnext[(size_t)m * H_DIM + j] = hv;
        if (t == sLen[mloc] - 1)
          last[(size_t)sOrd[mloc] * H_DIM + j] = hv;
      }
    }
  }
}

// ------------------------------------------------------------------
// Generic 128x128 BT-style f16 MFMA GEMM with on-the-fly f32->f16 hi/lo split.
// AMODE 0: A f32 [M,K].  AMODE 1: A = bitmask (u32 words, K/32 per row) -> 0/1 f16.
// BMODE 0: B f32 [K,N] (transposed+split in staging). BMODE 1: B pre-split f16 [N,K] hi/lo.
// NTERMS: 1 = Ah*Bh; 2 = +Al*Bh; 3 = +Ah*Bl.
// EPI: 0 store C f32; 1 threshold->bitmask (ballot) ; 2 store C*scale_m[m];
//      3 atomicAdd C += val*scale_m[m].
template<int AMODE, int BMODE, int NTERMS, int EPI>
__global__ __launch_bounds__(256)
void k_gemm(const float* __restrict__ A, const void* __restrict__ B0v,
            const void* __restrict__ B1v, const u32* __restrict__ Abits,
            float* __restrict__ C, u16* __restrict__ bitsOut,
            const float* __restrict__ scale_m, const float* __restrict__ phi_p,
            int M, int Nn, int K, int kLen) {
  int n0 = blockIdx.x * 128;
  int m0 = blockIdx.y * 128;
  int kStart = blockIdx.z * kLen;
  __shared__ f16 Ah[128 * 40];
  __shared__ f16 Al[128 * 40];
  __shared__ f16 Bh[128 * 40];
  __shared__ f16 Bl[128 * 40];
  int tid = threadIdx.x;
  int lane = tid & 63, wid = tid >> 6;
  int wm = wid & 1, wn = wid >> 1;
  int quad = lane >> 4, mr = lane & 15;
  f32x4 acc[4][4] = {};
  const int nkt = kLen >> 5;
  for (int kt = 0; kt < nkt; ++kt) {
    int kg = kStart + (kt << 5);
    if (AMODE == 0) {
#pragma unroll
      for (int i = 0; i < 4; ++i) {
        int q = tid + 256 * i;          // 1024 float4: 128 rows x 8
        int row = q >> 3, kc = (q & 7) << 2;
        float4 v = *reinterpret_cast<const float4*>(&A[(size_t)(m0 + row) * K + kg + kc]);
        f16 h0_ = (f16)v.x, h1_ = (f16)v.y, h2_ = (f16)v.z, h3_ = (f16)v.w;
        f16x4 hh; hh[0] = h0_; hh[1] = h1_; hh[2] = h2_; hh[3] = h3_;
        *reinterpret_cast<f16x4*>(&Ah[row * 40 + kc]) = hh;
        if (NTERMS >= 2) {
          f16x4 hl;
          hl[0] = (f16)(v.x - (float)h0_); hl[1] = (f16)(v.y - (float)h1_);
          hl[2] = (f16)(v.z - (float)h2_); hl[3] = (f16)(v.w - (float)h3_);
          *reinterpret_cast<f16x4*>(&Al[row * 40 + kc]) = hl;
        }
      }
    } else {
      if (tid < 128) {
        int row = tid;
        u32 w = Abits[(size_t)(m0 + row) * (K >> 5) + (kg >> 5)];
        u32* dst = reinterpret_cast<u32*>(&Ah[row * 40]);
#pragma unroll
        for (int p = 0; p < 16; ++p) {
          union { f16 h[2]; u32 u; } pk;
          pk.h[0] = ((w >> (2 * p)) & 1u) ? (f16)1.0f : (f16)0.0f;
          pk.h[1] = ((w >> (2 * p + 1)) & 1u) ? (f16)1.0f : (f16)0.0f;
          dst[p] = pk.u;
        }
      }
    }
    if (BMODE == 0) {
      const float* Bf = (const float*)B0v;
#pragma unroll
      for (int i = 0; i < 4; ++i) {
        int q = tid + 256 * i;          // 1024 float4: 32 krows x 32
        int krow = q >> 5, nc = (q & 31) << 2;
        float4 v = *reinterpret_cast<const float4*>(&Bf[(size_t)(kg + krow) * Nn + n0 + nc]);
        f16 h0_ = (f16)v.x, h1_ = (f16)v.y, h2_ = (f16)v.z, h3_ = (f16)v.w;
        Bh[(nc + 0) * 40 + krow] = h0_;
        Bh[(nc + 1) * 40 + krow] = h1_;
        Bh[(nc + 2) * 40 + krow] = h2_;
        Bh[(nc + 3) * 40 + krow] = h3_;
        if (NTERMS == 3) {
          Bl[(nc + 0) * 40 + krow] = (f16)(v.x - (float)h0_);
          Bl[(nc + 1) * 40 + krow] = (f16)(v.y - (float)h1_);
          Bl[(nc + 2) * 40 + krow] = (f16)(v.z - (float)h2_);
          Bl[(nc + 3) * 40 + krow] = (f16)(v.w - (float)h3_);
        }
      }
    } else {
      const f16* Bhi = (const f16*)B0v;
      const f16* Blo = (const f16*)B1v;
#pragma unroll
      for (int i = 0; i < 2; ++i) {
        int c = tid + 256 * i;          // 512 chunks of 8 f16
        int row = c >> 2, kc = (c & 3) << 3;
        f16x8 v = *reinterpret_cast<const f16x8*>(&Bhi[(size_t)(n0 + row) * K + kg + kc]);
        *reinterpret_cast<f16x8*>(&Bh[row * 40 + kc]) = v;
        if (NTERMS == 3) {
          f16x8 v2 = *reinterpret_cast<const f16x8*>(&Blo[(size_t)(n0 + row) * K + kg + kc]);
          *reinterpret_cast<f16x8*>(&Bl[row * 40 + kc]) = v2;
        }
      }
    }
    __syncthreads();
    f16x8 af[4], bf[4], alr[4], blr[4];
#pragma unroll
    for (int im = 0; im < 4; ++im) {
      af[im] = *reinterpret_cast<const f16x8*>(&Ah[(wm * 64 + im * 16 + mr) * 40 + quad * 8]);
      if (NTERMS >= 2)
        alr[im] = *reinterpret_cast<const f16x8*>(&Al[(wm * 64 + im * 16 + mr) * 40 + quad * 8]);
    }
#pragma unroll
    for (int in = 0; in < 4; ++in) {
      bf[in] = *reinterpret_cast<const f16x8*>(&Bh[(wn * 64 + in * 16 + mr) * 40 + quad * 8]);
      if (NTERMS == 3)
        blr[in] = *reinterpret_cast<const f16x8*>(&Bl[(wn * 64 + in * 16 + mr) * 40 + quad * 8]);
    }
#pragma unroll
    for (int im = 0; im < 4; ++im)
#pragma unroll
      for (int in = 0; in < 4; ++in) {
        acc[im][in] = __builtin_amdgcn_mfma_f32_16x16x32_f16(af[im], bf[in], acc[im][in], 0, 0, 0);
        if (NTERMS >= 2)
          acc[im][in] = __builtin_amdgcn_mfma_f32_16x16x32_f16(alr[im], bf[in], acc[im][in], 0, 0, 0);
        if (NTERMS == 3)
          acc[im][in] = __builtin_amdgcn_mfma_f32_16x16x32_f16(af[im], blr[in], acc[im][in], 0, 0, 0);
      }
    __syncthreads();
  }
  float phiK = 0.0f;
  if (EPI == 1) phiK = phi_p[0] * 65536.0f;   // adj = dot/65536 >= phi  <=>  dot >= phi*65536 (exact, pow2)
#pragma unroll
  for (int im = 0; im < 4; ++im) {
#pragma unroll
    for (int in = 0; in < 4; ++in) {
      int nn = n0 + wn * 64 + in * 16 + mr;
      int mb = m0 + wm * 64 + im * 16 + quad * 4;
#pragma unroll
      for (int r = 0; r < 4; ++r) {
        int m = mb + r;
        float v = acc[im][in][r];
        if (EPI == 0) {
          C[(size_t)m * Nn + nn] = v;
        } else if (EPI == 2) {
          C[(size_t)m * Nn + nn] = v * scale_m[m];
        } else if (EPI == 3) {
          atomicAdd(&C[(size_t)m * Nn + nn], v * scale_m[m]);
        } else if (EPI == 1) {
          bool one = (v >= phiK) || (m == nn);    // diag forced to 1
          u64 bal = __ballot(one);
          if (mr == 0) {
            u16 chunk = (u16)((bal >> (16 * quad)) & 0xFFFFu);
            bitsOut[(size_t)m * (Nn >> 4) + (nn >> 4)] = chunk;
          }
        }
      }
    }
  }
}

// ------------------------------------------------------------------
__global__ void k_add_bias(const float* __restrict__ src, const float* __restrict__ b,
                           float* __restrict__ dst) {
  int i = blockIdx.x * 256 + threadIdx.x;   // N*H
  dst[i] = src[i] + b[i & (H_DIM - 1)];
}

__global__ void k_scatter1(const int* __restrict__ he, const float* __restrict__ xw,
                           float* __restrict__ e) {
  int id = blockIdx.x * 256 + threadIdx.x;  // NNZ*64
  int nz = id >> 6, c = (id & 63) << 2;
  int node = he[nz], edge = he[NNZ_ + nz];
  float4 v = *reinterpret_cast<const float4*>(&xw[(size_t)node * H_DIM + c]);
  float* dst = &e[(size_t)edge * H_DIM + c];
  atomicAdd(dst + 0, v.x); atomicAdd(dst + 1, v.y);
  atomicAdd(dst + 2, v.z); atomicAdd(dst + 3, v.w);
}

__global__ void k_scatter2(const int* __restrict__ he, const float* __restrict__ e,
                           const float* __restrict__ binv, const float* __restrict__ dinv,
                           float* __restrict__ out) {
  int id = blockIdx.x * 256 + threadIdx.x;
  int nz = id >> 6, c = (id & 63) << 2;
  int node = he[nz], edge = he[NNZ_ + nz];
  float s = binv[edge] * dinv[node];
  float4 v = *reinterpret_cast<const float4*>(&e[(size_t)edge * H_DIM + c]);
  float* dst = &out[(size_t)node * H_DIM + c];
  atomicAdd(dst + 0, v.x * s); atomicAdd(dst + 1, v.y * s);
  atomicAdd(dst + 2, v.z * s); atomicAdd(dst + 3, v.w * s);
}

__global__ void k_split16(const float* __restrict__ src, f16* __restrict__ hi,
                          f16* __restrict__ lo) {
  int i = blockIdx.x * 256 + threadIdx.x;   // N*H
  float v = src[i];
  f16 h = (f16)v;
  hi[i] = h; lo[i] = (f16)(v - (float)h);
}

__global__ void k_degdis(const u32* __restrict__ bits, float* __restrict__ dis) {
  __shared__ int red[4];
  int row = blockIdx.x, tid = threadIdx.x;
  u32 w = bits[(size_t)row * 256 + tid];
  int c = __popc(w);
  for (int off = 32; off > 0; off >>= 1) c += __shfl_down(c, off);
  if ((tid & 63) == 0) red[tid >> 6] = c;
  __syncthreads();
  if (tid == 0) {
    int s = red[0] + red[1] + red[2] + red[3];
    dis[row] = s > 0 ? rsqrtf((float)s) : 0.0f;
  }
}

__global__ void k_outinit(const float* __restrict__ b, float* __restrict__ out) {
  int i = blockIdx.x * 256 + threadIdx.x;
  out[i] = b[i & (H_DIM - 1)];
}

// ------------------------------------------------------------------
extern "C" void kernel_launch(void* const* d_in, const int* in_sizes, int n_in,
                              void* d_out, int out_size, void* d_ws, size_t ws_size,
                              hipStream_t stream) {
  (void)in_sizes; (void)n_in; (void)out_size; (void)ws_size;
  const float* x    = (const float*)d_in[0];
  const int*   he   = (const int*)d_in[1];
  const int*   slen = (const int*)d_in[2];
  const float* h0   = (const float*)d_in[3];
  const float* wih  = (const float*)d_in[4];
  const float* whh  = (const float*)d_in[5];
  const float* bih  = (const float*)d_in[6];
  const float* bhh  = (const float*)d_in[7];
  const float* hw[3] = {(const float*)d_in[8], (const float*)d_in[10], (const float*)d_in[12]};
  const float* hb[3] = {(const float*)d_in[9], (const float*)d_in[11], (const float*)d_in[13]};
  const float* phi  = (const float*)d_in[14];
  const float* gw   = (const float*)d_in[15];
  const float* gb   = (const float*)d_in[16];
  float* out = (float*)d_out;

  // ---- workspace layout (~62 MB), everything re-initialized every call ----
  size_t off = 0;
  char* wsb = (char*)d_ws;
  auto alloc = [&](size_t b) { void* p = wsb + off; off += (b + 255) & ~(size_t)255; return p; };
  int*   order = (int*)alloc(N_NODES * 4);
  int*   lens  = (int*)alloc(N_NODES * 4);
  int*   Mts   = (int*)alloc(256);
  u32*   histD = (u32*)alloc(N_NODES * 4);
  u32*   histB = (u32*)alloc(N_EDGES * 4);
  float* dinv  = (float*)alloc(N_NODES * 4);
  float* binv  = (float*)alloc(N_EDGES * 4);
  float* dis   = (float*)alloc(N_NODES * 4);
  f16*   wih16 = (f16*)alloc(768 * 256 * 2);
  f16*   whh16 = (f16*)alloc(768 * 256 * 2);
  float* ha    = (float*)alloc((size_t)N_NODES * H_DIM * 4);
  float* hb2   = (float*)alloc((size_t)N_NODES * H_DIM * 4);
  float* oA    = (float*)alloc((size_t)N_NODES * H_DIM * 4);   // `last`, then o2
  float* oB    = (float*)alloc((size_t)N_NODES * H_DIM * 4);   // o1, then o3
  float* xwb   = (float*)alloc((size_t)N_NODES * H_DIM * 4);   // xw scratch / z
  float* eb    = (float*)alloc((size_t)N_EDGES * H_DIM * 4);
  f16*   o3hi  = (f16*)alloc((size_t)N_NODES * H_DIM * 2);
  f16*   o3lo  = (f16*)alloc((size_t)N_NODES * H_DIM * 2);
  u32*   Abits = (u32*)alloc((size_t)N_NODES * 256 * 4);       // 8192x8192 bits

  // ---- preprocessing ----
  k_sort<<<1, 256, 0, stream>>>(slen, order, lens, Mts);
  k_w16<<<768, 256, 0, stream>>>(wih, whh, wih16, whh16);
  k_hinit<<<N_NODES, 256, 0, stream>>>(h0, ha);
  hipMemsetAsync(histD, 0, N_NODES * 4, stream);
  hipMemsetAsync(histB, 0, N_EDGES * 4, stream);
  k_hist<<<NNZ_ / 256, 256, 0, stream>>>(he, histD, histB);
  k_inv<<<N_NODES / 256, 256, 0, stream>>>(histD, histB, dinv, binv);

  // ---- GRU: 32 fused steps, length-sorted with device-side early exit ----
  float* hcur = ha; float* hnxt = hb2;
  for (int t = 0; t < T_STEPS; ++t) {
    k_gru_step<<<dim3(4, 128), 256, 0, stream>>>(x, hcur, hnxt, oA, wih16, whh16,
                                                 bih, bhh, order, lens, Mts, t);
    float* tmp = hcur; hcur = hnxt; hnxt = tmp;
  }
  // oA now holds `last` in original node order.

  // ---- 3x HypergraphConv with residual ----
  float* prev = oA; float* nxt = oB;
  for (int c = 0; c < 3; ++c) {
    k_gemm<0, 0, 3, 0><<<dim3(2, 64, 1), 256, 0, stream>>>(
        prev, hw[c], nullptr, nullptr, xwb, nullptr, nullptr, nullptr,
        N_NODES, H_DIM, H_DIM, H_DIM);
    hipMemsetAsync(eb, 0, (size_t)N_EDGES * H_DIM * 4, stream);
    k_add_bias<<<N_NODES, 256, 0, stream>>>(prev, hb[c], nxt);   // residual + bias
    k_scatter1<<<NNZ_ * 64 / 256, 256, 0, stream>>>(he, xwb, eb);
    k_scatter2<<<NNZ_ * 64 / 256, 256, 0, stream>>>(he, eb, binv, dinv, nxt);
    float* tmp = prev; prev = nxt; nxt = tmp;
  }
  float* o3 = prev;  // == oB after 3 swaps

  // ---- dynamic adjacency: gram -> bitmask, degrees ----
  k_split16<<<N_NODES, 256, 0, stream>>>(o3, o3hi, o3lo);
  k_gemm<0, 1, 3, 1><<<dim3(64, 64, 1), 256, 0, stream>>>(
      o3, o3hi, o3lo, nullptr, nullptr, (u16*)Abits, nullptr, phi,
      N_NODES, N_NODES, H_DIM, H_DIM);
  k_degdis<<<N_NODES, 256, 0, stream>>>(Abits, dis);

  // ---- z = dis .* (o3 @ gcn_w) ----
  k_gemm<0, 0, 3, 2><<<dim3(2, 64, 1), 256, 0, stream>>>(
      o3, gw, nullptr, nullptr, xwb, nullptr, dis, nullptr,
      N_NODES, H_DIM, H_DIM, H_DIM);

  // ---- out = dis .* (A @ z) + gcn_b  (bitmask A expanded in LDS, split-K=4) ----
  k_outinit<<<N_NODES, 256, 0, stream>>>(gb, out);
  k_gemm<1, 0, 1, 3><<<dim3(2, 64, 4), 256, 0, stream>>>(
      nullptr, xwb, nullptr, Abits, out, nullptr, dis, nullptr,
      N_NODES, H_DIM, N_NODES, N_NODES / 4);
}

// Round 2
// 1722.362 us; speedup vs baseline: 1.7318x; 1.7318x over previous
//
#include <hip/hip_runtime.h>
#include <cstdint>
#include <cstddef>

typedef _Float16 f16;
typedef __attribute__((ext_vector_type(4))) _Float16 f16x4;
typedef __attribute__((ext_vector_type(8))) _Float16 f16x8;
typedef __attribute__((ext_vector_type(4))) float f32x4;
typedef uint32_t u32;
typedef uint16_t u16;
typedef unsigned long long u64;

#define N_NODES 8192
#define T_STEPS 32
#define H_DIM   256
#define N_EDGES 1024
#define NNZ_    65536

// ------------------------------------------------------------------
// counting sort of nodes by length, descending. Also emits M_t = #{len>t}.
__global__ void k_sort(const int* __restrict__ len, int* __restrict__ order,
                       int* __restrict__ len_s, int* __restrict__ Mts) {
  __shared__ int hist[33];
  __shared__ int cur[33];
  int tid = threadIdx.x;
  if (tid < 33) hist[tid] = 0;
  __syncthreads();
  for (int i = tid; i < N_NODES; i += 256) {
    int l = len[i]; l = l < 0 ? 0 : (l > 32 ? 32 : l);
    atomicAdd(&hist[l], 1);
  }
  __syncthreads();
  if (tid == 0) {
    int acc = 0;
    for (int l = 32; l >= 0; --l) { cur[l] = acc; acc += hist[l]; }
    for (int t = 0; t < 32; ++t) Mts[t] = cur[t];  // cur[t] = #{len > t}
  }
  __syncthreads();
  for (int i = tid; i < N_NODES; i += 256) {
    int l = len[i]; l = l < 0 ? 0 : (l > 32 ? 32 : l);
    int pos = atomicAdd(&cur[l], 1);
    order[pos] = i; len_s[pos] = l;
  }
}

__global__ void k_w16(const float* __restrict__ wih, const float* __restrict__ whh,
                      f16* __restrict__ wih16, f16* __restrict__ whh16) {
  int i = blockIdx.x * 256 + threadIdx.x;
  if (i < 768 * 256) { wih16[i] = (f16)wih[i]; whh16[i] = (f16)whh[i]; }
}

__global__ void k_hinit(const float* __restrict__ h0, float* __restrict__ h) {
  int i = blockIdx.x * 256 + threadIdx.x;   // N_NODES*H_DIM threads
  h[i] = h0[i & (H_DIM - 1)];
}

__global__ void k_hist(const int* __restrict__ he, u32* __restrict__ hd, u32* __restrict__ hb) {
  int i = blockIdx.x * 256 + threadIdx.x;
  if (i < NNZ_) {
    atomicAdd(&hd[he[i]], 1u);
    atomicAdd(&hb[he[NNZ_ + i]], 1u);
  }
}

__global__ void k_inv(const u32* __restrict__ hd, const u32* __restrict__ hb,
                      float* __restrict__ dinv, float* __restrict__ binv) {
  int i = blockIdx.x * 256 + threadIdx.x;
  if (i < N_NODES) dinv[i] = hd[i] ? 1.0f / (float)hd[i] : 0.0f;
  if (i < N_EDGES) binv[i] = hb[i] ? 1.0f / (float)hb[i] : 0.0f;
}

// ------------------------------------------------------------------
// Exclusive prefix scan of node/edge histograms -> CSR offsets + cursors.
// Single block, 256 threads, chunked Hillis-Steele.
__global__ void k_scan(const u32* __restrict__ histD, const u32* __restrict__ histB,
                       int* __restrict__ noff, int* __restrict__ eoff,
                       int* __restrict__ ncur, int* __restrict__ ecur) {
  __shared__ int buf[256];
  __shared__ int base;
  int tid = threadIdx.x;
  if (tid == 0) base = 0;
  __syncthreads();
  for (int ch = 0; ch < N_NODES / 256; ++ch) {
    int i = ch * 256 + tid;
    int v = (int)histD[i];
    buf[tid] = v; __syncthreads();
    for (int off = 1; off < 256; off <<= 1) {
      int t = (tid >= off) ? buf[tid - off] : 0; __syncthreads();
      buf[tid] += t; __syncthreads();
    }
    int excl = base + buf[tid] - v;
    noff[i] = excl; ncur[i] = excl;
    __syncthreads();
    if (tid == 255) { base += buf[255]; if (i == N_NODES - 1) noff[N_NODES] = base; }
    __syncthreads();
  }
  if (tid == 0) base = 0;
  __syncthreads();
  for (int ch = 0; ch < N_EDGES / 256; ++ch) {
    int i = ch * 256 + tid;
    int v = (int)histB[i];
    buf[tid] = v; __syncthreads();
    for (int off = 1; off < 256; off <<= 1) {
      int t = (tid >= off) ? buf[tid - off] : 0; __syncthreads();
      buf[tid] += t; __syncthreads();
    }
    int excl = base + buf[tid] - v;
    eoff[i] = excl; ecur[i] = excl;
    __syncthreads();
    if (tid == 255) { base += buf[255]; if (i == N_EDGES - 1) eoff[N_EDGES] = base; }
    __syncthreads();
  }
}

__global__ void k_fill(const int* __restrict__ he, int* __restrict__ ncur,
                       int* __restrict__ ecur, int* __restrict__ nlist,
                       int* __restrict__ elist) {
  int i = blockIdx.x * 256 + threadIdx.x;
  if (i < NNZ_) {
    int node = he[i], edge = he[NNZ_ + i];
    int p1 = atomicAdd(&ecur[edge], 1); nlist[p1] = node;  // per-edge node list
    int p2 = atomicAdd(&ncur[node], 1); elist[p2] = edge;  // per-node edge list
  }
}

// e[edge][c] = Binv[edge] * sum_{node in edge} xw[node][c]   (gather, no atomics)
__global__ __launch_bounds__(256)
void k_edge_gather(const float* __restrict__ xw, const int* __restrict__ eoff,
                   const int* __restrict__ nlist, const float* __restrict__ binv,
                   float* __restrict__ e) {
  int edge = blockIdx.x, c = threadIdx.x;
  int s = eoff[edge], t = eoff[edge + 1];
  __shared__ int nds[256];
  float sum = 0.0f;
  for (int base = s; base < t; base += 256) {
    int nchunk = t - base; if (nchunk > 256) nchunk = 256;
    if (c < nchunk) nds[c] = nlist[base + c];
    __syncthreads();
    for (int k = 0; k < nchunk; ++k)
      sum += xw[(size_t)nds[k] * H_DIM + c];
    __syncthreads();
  }
  e[(size_t)edge * H_DIM + c] = sum * binv[edge];
}

// out[node][c] = prev[node][c] + bias[c] + Dinv[node] * sum_{edge in node} e[edge][c]
__global__ __launch_bounds__(256)
void k_node_gather(const float* __restrict__ e, const int* __restrict__ noff,
                   const int* __restrict__ elist, const float* __restrict__ dinv,
                   const float* __restrict__ prev, const float* __restrict__ bias,
                   float* __restrict__ outp) {
  int node = blockIdx.x, c = threadIdx.x;
  int s = noff[node], t = noff[node + 1];
  __shared__ int eds[64];
  float sum = 0.0f;
  for (int base = s; base < t; base += 64) {
    int nchunk = t - base; if (nchunk > 64) nchunk = 64;
    if (c < nchunk) eds[c] = elist[base + c];
    __syncthreads();
    for (int k = 0; k < nchunk; ++k)
      sum += e[(size_t)eds[k] * H_DIM + c];
    __syncthreads();
  }
  outp[(size_t)node * H_DIM + c] =
      prev[(size_t)node * H_DIM + c] + bias[c] + dinv[node] * sum;
}

// ------------------------------------------------------------------
// One GRU time step, fused input+recurrent GEMM + cell epilogue.
// Sorted node space; h split hi/lo (f16x2) so per-step quantization does not accumulate.
// Tile: BM=64 nodes x BN=64 gate-dims, K=256, 4 waves (each 64x16).
__global__ __launch_bounds__(256)
void k_gru_step(const float* __restrict__ x, const float* __restrict__ hprev,
                float* __restrict__ hnext, float* __restrict__ last,
                const f16* __restrict__ wih, const f16* __restrict__ whh,
                const float* __restrict__ bih, const float* __restrict__ bhh,
                const int* __restrict__ order, const int* __restrict__ len_s,
                const int* __restrict__ Mts, int t) {
  int Mt = Mts[t];
  int m0 = blockIdx.y * 64;
  if (m0 >= Mt) return;
  int j0 = blockIdx.x * 64;
  __shared__ f16 Ax[64 * 40], Ahh[64 * 40], Ahl[64 * 40];
  __shared__ f16 Bw[6][64 * 40];   // 0..2: W_ih r,z,n  3..5: W_hh r,z,n
  __shared__ int sOrd[64], sLen[64];
  int tid = threadIdx.x;
  if (tid < 64) {
    int g = m0 + tid; if (g > Mt - 1) g = Mt - 1;
    sOrd[tid] = order[g]; sLen[tid] = len_s[g];
  }
  __syncthreads();

  int lane = tid & 63, wid = tid >> 6;
  int quad = lane >> 4, mr = lane & 15;
  f32x4 accR[4] = {}, accZ[4] = {}, accXN[4] = {}, accHN[4] = {};

  for (int kt = 0; kt < 8; ++kt) {
    int k0 = kt * 32;
#pragma unroll
    for (int i = 0; i < 2; ++i) {
      int q = tid + 256 * i;            // 512 float4: 64 rows x 8 f4
      int row = q >> 3, kc = (q & 7) << 2;
      int rclamp = m0 + row; if (rclamp > Mt - 1) rclamp = Mt - 1;
      const float4 vx = *reinterpret_cast<const float4*>(
          &x[(size_t)sOrd[row] * (T_STEPS * H_DIM) + (size_t)t * H_DIM + k0 + kc]);
      f16x4 hx;
      hx[0] = (f16)vx.x; hx[1] = (f16)vx.y; hx[2] = (f16)vx.z; hx[3] = (f16)vx.w;
      *reinterpret_cast<f16x4*>(&Ax[row * 40 + kc]) = hx;
      const float4 vh = *reinterpret_cast<const float4*>(
          &hprev[(size_t)rclamp * H_DIM + k0 + kc]);
      f16 h0_ = (f16)vh.x, h1_ = (f16)vh.y, h2_ = (f16)vh.z, h3_ = (f16)vh.w;
      f16x4 hh, hl;
      hh[0] = h0_; hh[1] = h1_; hh[2] = h2_; hh[3] = h3_;
      hl[0] = (f16)(vh.x - (float)h0_); hl[1] = (f16)(vh.y - (float)h1_);
      hl[2] = (f16)(vh.z - (float)h2_); hl[3] = (f16)(vh.w - (float)h3_);
      *reinterpret_cast<f16x4*>(&Ahh[row * 40 + kc]) = hh;
      *reinterpret_cast<f16x4*>(&Ahl[row * 40 + kc]) = hl;
    }
#pragma unroll
    for (int i = 0; i < 6; ++i) {
      int c = tid + 256 * i;            // 1536 chunks of 8 f16
      int mat = c >> 8, cc = c & 255;
      int row = cc >> 2, kc = (cc & 3) << 3;
      const f16* src = (mat < 3) ? wih : whh;
      int gate = (mat < 3) ? mat : mat - 3;
      f16x8 v = *reinterpret_cast<const f16x8*>(
          &src[(size_t)(gate * 256 + j0 + row) * 256 + k0 + kc]);
      *reinterpret_cast<f16x8*>(&Bw[mat][row * 40 + kc]) = v;
    }
    __syncthreads();
    f16x8 bfr[6];
#pragma unroll
    for (int mmt = 0; mmt < 6; ++mmt)
      bfr[mmt] = *reinterpret_cast<const f16x8*>(&Bw[mmt][(wid * 16 + mr) * 40 + quad * 8]);
#pragma unroll
    for (int im = 0; im < 4; ++im) {
      f16x8 ax = *reinterpret_cast<const f16x8*>(&Ax[(im * 16 + mr) * 40 + quad * 8]);
      f16x8 ah = *reinterpret_cast<const f16x8*>(&Ahh[(im * 16 + mr) * 40 + quad * 8]);
      f16x8 al = *reinterpret_cast<const f16x8*>(&Ahl[(im * 16 + mr) * 40 + quad * 8]);
      accR[im]  = __builtin_amdgcn_mfma_f32_16x16x32_f16(ax, bfr[0], accR[im], 0, 0, 0);
      accR[im]  = __builtin_amdgcn_mfma_f32_16x16x32_f16(ah, bfr[3], accR[im], 0, 0, 0);
      accR[im]  = __builtin_amdgcn_mfma_f32_16x16x32_f16(al, bfr[3], accR[im], 0, 0, 0);
      accZ[im]  = __builtin_amdgcn_mfma_f32_16x16x32_f16(ax, bfr[1], accZ[im], 0, 0, 0);
      accZ[im]  = __builtin_amdgcn_mfma_f32_16x16x32_f16(ah, bfr[4], accZ[im], 0, 0, 0);
      accZ[im]  = __builtin_amdgcn_mfma_f32_16x16x32_f16(al, bfr[4], accZ[im], 0, 0, 0);
      accXN[im] = __builtin_amdgcn_mfma_f32_16x16x32_f16(ax, bfr[2], accXN[im], 0, 0, 0);
      accHN[im] = __builtin_amdgcn_mfma_f32_16x16x32_f16(ah, bfr[5], accHN[im], 0, 0, 0);
      accHN[im] = __builtin_amdgcn_mfma_f32_16x16x32_f16(al, bfr[5], accHN[im], 0, 0, 0);
    }
    __syncthreads();
  }
  // epilogue: GRU cell. C/D layout: col=lane&15 (j), row=quad*4+reg (m).
  int j = j0 + wid * 16 + mr;
  float bir = bih[j], biz = bih[256 + j], bin_ = bih[512 + j];
  float bhr = bhh[j], bhz = bhh[256 + j], bhn = bhh[512 + j];
#pragma unroll
  for (int im = 0; im < 4; ++im) {
#pragma unroll
    for (int r = 0; r < 4; ++r) {
      int mloc = im * 16 + quad * 4 + r;
      int m = m0 + mloc;
      if (m < Mt) {
        float rg = 1.0f / (1.0f + expf(-(accR[im][r] + bir + bhr)));
        float zg = 1.0f / (1.0f + expf(-(accZ[im][r] + biz + bhz)));
        float ng = tanhf(accXN[im][r] + bin_ + rg * (accHN[im][r] + bhn));
        float hp = hprev[(size_t)m * H_DIM + j];
        float hv = (1.0f - zg) * ng + zg * hp;
        hnext[(size_t)m * H_DIM + j] = hv;
        if (t == sLen[mloc] - 1)
          last[(size_t)sOrd[mloc] * H_DIM + j] = hv;
      }
    }
  }
}

// ------------------------------------------------------------------
// Generic 128x128 BT-style f16 MFMA GEMM with on-the-fly f32->f16 hi/lo split.
// AMODE 0: A f32 [M,K].  AMODE 1: A = bitmask (u32 words, K/32 per row) -> 0/1 f16.
// BMODE 0: B f32 [K,N] (transposed+split in staging). BMODE 1: B pre-split f16 [N,K] hi/lo.
// NTERMS: 1 = Ah*Bh; 2 = +Al*Bh; 3 = +Ah*Bl.
// EPI: 0 store C f32; 1 threshold->bitmask (ballot) ; 2 store C*scale_m[m];
//      3 atomicAdd C += val*scale_m[m].
template<int AMODE, int BMODE, int NTERMS, int EPI>
__global__ __launch_bounds__(256)
void k_gemm(const float* __restrict__ A, const void* __restrict__ B0v,
            const void* __restrict__ B1v, const u32* __restrict__ Abits,
            float* __restrict__ C, u16* __restrict__ bitsOut,
            const float* __restrict__ scale_m, const float* __restrict__ phi_p,
            int M, int Nn, int K, int kLen) {
  int n0 = blockIdx.x * 128;
  int m0 = blockIdx.y * 128;
  int kStart = blockIdx.z * kLen;
  __shared__ f16 Ah[128 * 40];
  __shared__ f16 Al[128 * 40];
  __shared__ f16 Bh[128 * 40];
  __shared__ f16 Bl[128 * 40];
  int tid = threadIdx.x;
  int lane = tid & 63, wid = tid >> 6;
  int wm = wid & 1, wn = wid >> 1;
  int quad = lane >> 4, mr = lane & 15;
  f32x4 acc[4][4] = {};
  const int nkt = kLen >> 5;
  for (int kt = 0; kt < nkt; ++kt) {
    int kg = kStart + (kt << 5);
    if (AMODE == 0) {
#pragma unroll
      for (int i = 0; i < 4; ++i) {
        int q = tid + 256 * i;          // 1024 float4: 128 rows x 8
        int row = q >> 3, kc = (q & 7) << 2;
        float4 v = *reinterpret_cast<const float4*>(&A[(size_t)(m0 + row) * K + kg + kc]);
        f16 h0_ = (f16)v.x, h1_ = (f16)v.y, h2_ = (f16)v.z, h3_ = (f16)v.w;
        f16x4 hh; hh[0] = h0_; hh[1] = h1_; hh[2] = h2_; hh[3] = h3_;
        *reinterpret_cast<f16x4*>(&Ah[row * 40 + kc]) = hh;
        if (NTERMS >= 2) {
          f16x4 hl;
          hl[0] = (f16)(v.x - (float)h0_); hl[1] = (f16)(v.y - (float)h1_);
          hl[2] = (f16)(v.z - (float)h2_); hl[3] = (f16)(v.w - (float)h3_);
          *reinterpret_cast<f16x4*>(&Al[row * 40 + kc]) = hl;
        }
      }
    } else {
      if (tid < 128) {
        int row = tid;
        u32 w = Abits[(size_t)(m0 + row) * (K >> 5) + (kg >> 5)];
        u32* dst = reinterpret_cast<u32*>(&Ah[row * 40]);
#pragma unroll
        for (int p = 0; p < 16; ++p) {
          union { f16 h[2]; u32 u; } pk;
          pk.h[0] = ((w >> (2 * p)) & 1u) ? (f16)1.0f : (f16)0.0f;
          pk.h[1] = ((w >> (2 * p + 1)) & 1u) ? (f16)1.0f : (f16)0.0f;
          dst[p] = pk.u;
        }
      }
    }
    if (BMODE == 0) {
      const float* Bf = (const float*)B0v;
#pragma unroll
      for (int i = 0; i < 4; ++i) {
        int q = tid + 256 * i;          // 1024 float4: 32 krows x 32
        int krow = q >> 5, nc = (q & 31) << 2;
        float4 v = *reinterpret_cast<const float4*>(&Bf[(size_t)(kg + krow) * Nn + n0 + nc]);
        f16 h0_ = (f16)v.x, h1_ = (f16)v.y, h2_ = (f16)v.z, h3_ = (f16)v.w;
        Bh[(nc + 0) * 40 + krow] = h0_;
        Bh[(nc + 1) * 40 + krow] = h1_;
        Bh[(nc + 2) * 40 + krow] = h2_;
        Bh[(nc + 3) * 40 + krow] = h3_;
        if (NTERMS == 3) {
          Bl[(nc + 0) * 40 + krow] = (f16)(v.x - (float)h0_);
          Bl[(nc + 1) * 40 + krow] = (f16)(v.y - (float)h1_);
          Bl[(nc + 2) * 40 + krow] = (f16)(v.z - (float)h2_);
          Bl[(nc + 3) * 40 + krow] = (f16)(v.w - (float)h3_);
        }
      }
    } else {
      const f16* Bhi = (const f16*)B0v;
      const f16* Blo = (const f16*)B1v;
#pragma unroll
      for (int i = 0; i < 2; ++i) {
        int c = tid + 256 * i;          // 512 chunks of 8 f16
        int row = c >> 2, kc = (c & 3) << 3;
        f16x8 v = *reinterpret_cast<const f16x8*>(&Bhi[(size_t)(n0 + row) * K + kg + kc]);
        *reinterpret_cast<f16x8*>(&Bh[row * 40 + kc]) = v;
        if (NTERMS == 3) {
          f16x8 v2 = *reinterpret_cast<const f16x8*>(&Blo[(size_t)(n0 + row) * K + kg + kc]);
          *reinterpret_cast<f16x8*>(&Bl[row * 40 + kc]) = v2;
        }
      }
    }
    __syncthreads();
    f16x8 af[4], bf[4], alr[4], blr[4];
#pragma unroll
    for (int im = 0; im < 4; ++im) {
      af[im] = *reinterpret_cast<const f16x8*>(&Ah[(wm * 64 + im * 16 + mr) * 40 + quad * 8]);
      if (NTERMS >= 2)
        alr[im] = *reinterpret_cast<const f16x8*>(&Al[(wm * 64 + im * 16 + mr) * 40 + quad * 8]);
    }
#pragma unroll
    for (int in = 0; in < 4; ++in) {
      bf[in] = *reinterpret_cast<const f16x8*>(&Bh[(wn * 64 + in * 16 + mr) * 40 + quad * 8]);
      if (NTERMS == 3)
        blr[in] = *reinterpret_cast<const f16x8*>(&Bl[(wn * 64 + in * 16 + mr) * 40 + quad * 8]);
    }
#pragma unroll
    for (int im = 0; im < 4; ++im)
#pragma unroll
      for (int in = 0; in < 4; ++in) {
        acc[im][in] = __builtin_amdgcn_mfma_f32_16x16x32_f16(af[im], bf[in], acc[im][in], 0, 0, 0);
        if (NTERMS >= 2)
          acc[im][in] = __builtin_amdgcn_mfma_f32_16x16x32_f16(alr[im], bf[in], acc[im][in], 0, 0, 0);
        if (NTERMS == 3)
          acc[im][in] = __builtin_amdgcn_mfma_f32_16x16x32_f16(af[im], blr[in], acc[im][in], 0, 0, 0);
      }
    __syncthreads();
  }
  float phiK = 0.0f;
  if (EPI == 1) phiK = phi_p[0] * 65536.0f;   // adj = dot/65536 >= phi  <=>  dot >= phi*65536 (exact, pow2)
#pragma unroll
  for (int im = 0; im < 4; ++im) {
#pragma unroll
    for (int in = 0; in < 4; ++in) {
      int nn = n0 + wn * 64 + in * 16 + mr;
      int mb = m0 + wm * 64 + im * 16 + quad * 4;
#pragma unroll
      for (int r = 0; r < 4; ++r) {
        int m = mb + r;
        float v = acc[im][in][r];
        if (EPI == 0) {
          C[(size_t)m * Nn + nn] = v;
        } else if (EPI == 2) {
          C[(size_t)m * Nn + nn] = v * scale_m[m];
        } else if (EPI == 3) {
          atomicAdd(&C[(size_t)m * Nn + nn], v * scale_m[m]);
        } else if (EPI == 1) {
          bool one = (v >= phiK) || (m == nn);    // diag forced to 1
          u64 bal = __ballot(one);
          if (mr == 0) {
            u16 chunk = (u16)((bal >> (16 * quad)) & 0xFFFFu);
            bitsOut[(size_t)m * (Nn >> 4) + (nn >> 4)] = chunk;
          }
        }
      }
    }
  }
}

// ------------------------------------------------------------------
__global__ void k_split16(const float* __restrict__ src, f16* __restrict__ hi,
                          f16* __restrict__ lo) {
  int i = blockIdx.x * 256 + threadIdx.x;   // N*H
  float v = src[i];
  f16 h = (f16)v;
  hi[i] = h; lo[i] = (f16)(v - (float)h);
}

__global__ void k_degdis(const u32* __restrict__ bits, float* __restrict__ dis) {
  __shared__ int red[4];
  int row = blockIdx.x, tid = threadIdx.x;
  u32 w = bits[(size_t)row * 256 + tid];
  int c = __popc(w);
  for (int off = 32; off > 0; off >>= 1) c += __shfl_down(c, off);
  if ((tid & 63) == 0) red[tid >> 6] = c;
  __syncthreads();
  if (tid == 0) {
    int s = red[0] + red[1] + red[2] + red[3];
    dis[row] = s > 0 ? rsqrtf((float)s) : 0.0f;
  }
}

__global__ void k_outinit(const float* __restrict__ b, float* __restrict__ out) {
  int i = blockIdx.x * 256 + threadIdx.x;
  out[i] = b[i & (H_DIM - 1)];
}

// ------------------------------------------------------------------
extern "C" void kernel_launch(void* const* d_in, const int* in_sizes, int n_in,
                              void* d_out, int out_size, void* d_ws, size_t ws_size,
                              hipStream_t stream) {
  (void)in_sizes; (void)n_in; (void)out_size; (void)ws_size;
  const float* x    = (const float*)d_in[0];
  const int*   he   = (const int*)d_in[1];
  const int*   slen = (const int*)d_in[2];
  const float* h0   = (const float*)d_in[3];
  const float* wih  = (const float*)d_in[4];
  const float* whh  = (const float*)d_in[5];
  const float* bih  = (const float*)d_in[6];
  const float* bhh  = (const float*)d_in[7];
  const float* hw[3] = {(const float*)d_in[8], (const float*)d_in[10], (const float*)d_in[12]};
  const float* hb[3] = {(const float*)d_in[9], (const float*)d_in[11], (const float*)d_in[13]};
  const float* phi  = (const float*)d_in[14];
  const float* gw   = (const float*)d_in[15];
  const float* gb   = (const float*)d_in[16];
  float* out = (float*)d_out;

  // ---- workspace layout (~63 MB), everything re-initialized every call ----
  size_t off = 0;
  char* wsb = (char*)d_ws;
  auto alloc = [&](size_t b) { void* p = wsb + off; off += (b + 255) & ~(size_t)255; return p; };
  int*   order = (int*)alloc(N_NODES * 4);
  int*   lens  = (int*)alloc(N_NODES * 4);
  int*   Mts   = (int*)alloc(256);
  u32*   histD = (u32*)alloc(N_NODES * 4);
  u32*   histB = (u32*)alloc(N_EDGES * 4);
  float* dinv  = (float*)alloc(N_NODES * 4);
  float* binv  = (float*)alloc(N_EDGES * 4);
  float* dis   = (float*)alloc(N_NODES * 4);
  int*   noff  = (int*)alloc((N_NODES + 1) * 4);
  int*   eoff  = (int*)alloc((N_EDGES + 1) * 4);
  int*   ncur  = (int*)alloc(N_NODES * 4);
  int*   ecur  = (int*)alloc(N_EDGES * 4);
  int*   nlist = (int*)alloc(NNZ_ * 4);   // per-edge node lists
  int*   elist = (int*)alloc(NNZ_ * 4);   // per-node edge lists
  f16*   wih16 = (f16*)alloc(768 * 256 * 2);
  f16*   whh16 = (f16*)alloc(768 * 256 * 2);
  float* ha    = (float*)alloc((size_t)N_NODES * H_DIM * 4);
  float* hb2   = (float*)alloc((size_t)N_NODES * H_DIM * 4);
  float* oA    = (float*)alloc((size_t)N_NODES * H_DIM * 4);   // `last`, then o2
  float* oB    = (float*)alloc((size_t)N_NODES * H_DIM * 4);   // o1, then o3
  float* xwb   = (float*)alloc((size_t)N_NODES * H_DIM * 4);   // xw scratch / z
  float* eb    = (float*)alloc((size_t)N_EDGES * H_DIM * 4);
  f16*   o3hi  = (f16*)alloc((size_t)N_NODES * H_DIM * 2);
  f16*   o3lo  = (f16*)alloc((size_t)N_NODES * H_DIM * 2);
  u32*   Abits = (u32*)alloc((size_t)N_NODES * 256 * 4);       // 8192x8192 bits

  // ---- preprocessing ----
  k_sort<<<1, 256, 0, stream>>>(slen, order, lens, Mts);
  k_w16<<<768, 256, 0, stream>>>(wih, whh, wih16, whh16);
  k_hinit<<<N_NODES, 256, 0, stream>>>(h0, ha);
  hipMemsetAsync(histD, 0, N_NODES * 4, stream);
  hipMemsetAsync(histB, 0, N_EDGES * 4, stream);
  k_hist<<<NNZ_ / 256, 256, 0, stream>>>(he, histD, histB);
  k_inv<<<N_NODES / 256, 256, 0, stream>>>(histD, histB, dinv, binv);
  k_scan<<<1, 256, 0, stream>>>(histD, histB, noff, eoff, ncur, ecur);
  k_fill<<<NNZ_ / 256, 256, 0, stream>>>(he, ncur, ecur, nlist, elist);

  // ---- GRU: 32 fused steps, length-sorted with device-side early exit ----
  float* hcur = ha; float* hnxt = hb2;
  for (int t = 0; t < T_STEPS; ++t) {
    k_gru_step<<<dim3(4, 128), 256, 0, stream>>>(x, hcur, hnxt, oA, wih16, whh16,
                                                 bih, bhh, order, lens, Mts, t);
    float* tmp = hcur; hcur = hnxt; hnxt = tmp;
  }
  // oA now holds `last` in original node order.

  // ---- 3x HypergraphConv with residual (CSR gather, no atomics) ----
  float* prev = oA; float* nxt = oB;
  for (int c = 0; c < 3; ++c) {
    k_gemm<0, 0, 3, 0><<<dim3(2, 64, 1), 256, 0, stream>>>(
        prev, hw[c], nullptr, nullptr, xwb, nullptr, nullptr, nullptr,
        N_NODES, H_DIM, H_DIM, H_DIM);
    k_edge_gather<<<N_EDGES, 256, 0, stream>>>(xwb, eoff, nlist, binv, eb);
    k_node_gather<<<N_NODES, 256, 0, stream>>>(eb, noff, elist, dinv, prev, hb[c], nxt);
    float* tmp = prev; prev = nxt; nxt = tmp;
  }
  float* o3 = prev;  // == oB after 3 swaps

  // ---- dynamic adjacency: gram -> bitmask, degrees ----
  k_split16<<<N_NODES, 256, 0, stream>>>(o3, o3hi, o3lo);
  k_gemm<0, 1, 3, 1><<<dim3(64, 64, 1), 256, 0, stream>>>(
      o3, o3hi, o3lo, nullptr, nullptr, (u16*)Abits, nullptr, phi,
      N_NODES, N_NODES, H_DIM, H_DIM);
  k_degdis<<<N_NODES, 256, 0, stream>>>(Abits, dis);

  // ---- z = dis .* (o3 @ gcn_w) ----
  k_gemm<0, 0, 3, 2><<<dim3(2, 64, 1), 256, 0, stream>>>(
      o3, gw, nullptr, nullptr, xwb, nullptr, dis, nullptr,
      N_NODES, H_DIM, H_DIM, H_DIM);

  // ---- out = dis .* (A @ z) + gcn_b  (bitmask A expanded in LDS, split-K=4) ----
  k_outinit<<<N_NODES, 256, 0, stream>>>(gb, out);
  k_gemm<1, 0, 1, 3><<<dim3(2, 64, 4), 256, 0, stream>>>(
      nullptr, xwb, nullptr, Abits, out, nullptr, dis, nullptr,
      N_NODES, H_DIM, N_NODES, N_NODES / 4);
}

// Round 3
// 1596.601 us; speedup vs baseline: 1.8682x; 1.0788x over previous
//
#include <hip/hip_runtime.h>
#include <cstdint>
#include <cstddef>

typedef _Float16 f16;
typedef __attribute__((ext_vector_type(4))) _Float16 f16x4;
typedef __attribute__((ext_vector_type(8))) _Float16 f16x8;
typedef __attribute__((ext_vector_type(4))) float f32x4;
typedef uint32_t u32;
typedef uint16_t u16;
typedef unsigned long long u64;

#define N_NODES 8192
#define T_STEPS 32
#define H_DIM   256
#define N_EDGES 1024
#define NNZ_    65536

// LDS row stride: 36 f16 = 18 words; mr*18 mod 32 has 16 distinct residues
// -> conflict-free fragment reads (vs 40 f16 = 20 words, period 8, 2-4x conflicts).
#define LSTR 36

__device__ __forceinline__ f16x8 ld8lds(const f16* p) {
  union { f16x8 v8; f16x4 v4[2]; } u;
  u.v4[0] = *reinterpret_cast<const f16x4*>(p);
  u.v4[1] = *reinterpret_cast<const f16x4*>(p + 4);
  return u.v8;
}
__device__ __forceinline__ void st8lds(f16* p, f16x8 v) {
  union { f16x8 v8; f16x4 v4[2]; } u; u.v8 = v;
  *reinterpret_cast<f16x4*>(p) = u.v4[0];
  *reinterpret_cast<f16x4*>(p + 4) = u.v4[1];
}

// ------------------------------------------------------------------
// counting sort of nodes by length, descending. Also emits M_t = #{len>t}.
__global__ void k_sort(const int* __restrict__ len, int* __restrict__ order,
                       int* __restrict__ len_s, int* __restrict__ Mts) {
  __shared__ int hist[33];
  __shared__ int cur[33];
  int tid = threadIdx.x;
  if (tid < 33) hist[tid] = 0;
  __syncthreads();
  for (int i = tid; i < N_NODES; i += 256) {
    int l = len[i]; l = l < 0 ? 0 : (l > 32 ? 32 : l);
    atomicAdd(&hist[l], 1);
  }
  __syncthreads();
  if (tid == 0) {
    int acc = 0;
    for (int l = 32; l >= 0; --l) { cur[l] = acc; acc += hist[l]; }
    for (int t = 0; t < 32; ++t) Mts[t] = cur[t];  // cur[t] = #{len > t}
  }
  __syncthreads();
  for (int i = tid; i < N_NODES; i += 256) {
    int l = len[i]; l = l < 0 ? 0 : (l > 32 ? 32 : l);
    int pos = atomicAdd(&cur[l], 1);
    order[pos] = i; len_s[pos] = l;
  }
}

__global__ void k_w16(const float* __restrict__ wih, const float* __restrict__ whh,
                      f16* __restrict__ wih16, f16* __restrict__ whh16) {
  int i = blockIdx.x * 256 + threadIdx.x;
  if (i < 768 * 256) { wih16[i] = (f16)wih[i]; whh16[i] = (f16)whh[i]; }
}

__global__ void k_hinit(const float* __restrict__ h0, float* __restrict__ h) {
  int i = blockIdx.x * 256 + threadIdx.x;   // N_NODES*H_DIM threads
  h[i] = h0[i & (H_DIM - 1)];
}

__global__ void k_hist(const int* __restrict__ he, u32* __restrict__ hd, u32* __restrict__ hb) {
  int i = blockIdx.x * 256 + threadIdx.x;
  if (i < NNZ_) {
    atomicAdd(&hd[he[i]], 1u);
    atomicAdd(&hb[he[NNZ_ + i]], 1u);
  }
}

__global__ void k_inv(const u32* __restrict__ hd, const u32* __restrict__ hb,
                      float* __restrict__ dinv, float* __restrict__ binv) {
  int i = blockIdx.x * 256 + threadIdx.x;
  if (i < N_NODES) dinv[i] = hd[i] ? 1.0f / (float)hd[i] : 0.0f;
  if (i < N_EDGES) binv[i] = hb[i] ? 1.0f / (float)hb[i] : 0.0f;
}

// ------------------------------------------------------------------
// Exclusive prefix scan of node/edge histograms -> CSR offsets + cursors.
__global__ void k_scan(const u32* __restrict__ histD, const u32* __restrict__ histB,
                       int* __restrict__ noff, int* __restrict__ eoff,
                       int* __restrict__ ncur, int* __restrict__ ecur) {
  __shared__ int buf[256];
  __shared__ int base;
  int tid = threadIdx.x;
  if (tid == 0) base = 0;
  __syncthreads();
  for (int ch = 0; ch < N_NODES / 256; ++ch) {
    int i = ch * 256 + tid;
    int v = (int)histD[i];
    buf[tid] = v; __syncthreads();
    for (int off = 1; off < 256; off <<= 1) {
      int t = (tid >= off) ? buf[tid - off] : 0; __syncthreads();
      buf[tid] += t; __syncthreads();
    }
    int excl = base + buf[tid] - v;
    noff[i] = excl; ncur[i] = excl;
    __syncthreads();
    if (tid == 255) { base += buf[255]; if (i == N_NODES - 1) noff[N_NODES] = base; }
    __syncthreads();
  }
  if (tid == 0) base = 0;
  __syncthreads();
  for (int ch = 0; ch < N_EDGES / 256; ++ch) {
    int i = ch * 256 + tid;
    int v = (int)histB[i];
    buf[tid] = v; __syncthreads();
    for (int off = 1; off < 256; off <<= 1) {
      int t = (tid >= off) ? buf[tid - off] : 0; __syncthreads();
      buf[tid] += t; __syncthreads();
    }
    int excl = base + buf[tid] - v;
    eoff[i] = excl; ecur[i] = excl;
    __syncthreads();
    if (tid == 255) { base += buf[255]; if (i == N_EDGES - 1) eoff[N_EDGES] = base; }
    __syncthreads();
  }
}

__global__ void k_fill(const int* __restrict__ he, int* __restrict__ ncur,
                       int* __restrict__ ecur, int* __restrict__ nlist,
                       int* __restrict__ elist) {
  int i = blockIdx.x * 256 + threadIdx.x;
  if (i < NNZ_) {
    int node = he[i], edge = he[NNZ_ + i];
    int p1 = atomicAdd(&ecur[edge], 1); nlist[p1] = node;  // per-edge node list
    int p2 = atomicAdd(&ncur[node], 1); elist[p2] = edge;  // per-node edge list
  }
}

// e[edge][c] = Binv[edge] * sum_{node in edge} xw[node][c]   (gather, no atomics)
__global__ __launch_bounds__(256)
void k_edge_gather(const float* __restrict__ xw, const int* __restrict__ eoff,
                   const int* __restrict__ nlist, const float* __restrict__ binv,
                   float* __restrict__ e) {
  int edge = blockIdx.x, c = threadIdx.x;
  int s = eoff[edge], t = eoff[edge + 1];
  __shared__ int nds[256];
  float sum = 0.0f;
  for (int base = s; base < t; base += 256) {
    int nchunk = t - base; if (nchunk > 256) nchunk = 256;
    if (c < nchunk) nds[c] = nlist[base + c];
    __syncthreads();
    for (int k = 0; k < nchunk; ++k)
      sum += xw[(size_t)nds[k] * H_DIM + c];
    __syncthreads();
  }
  e[(size_t)edge * H_DIM + c] = sum * binv[edge];
}

// out[node][c] = prev[node][c] + bias[c] + Dinv[node] * sum_{edge in node} e[edge][c]
__global__ __launch_bounds__(256)
void k_node_gather(const float* __restrict__ e, const int* __restrict__ noff,
                   const int* __restrict__ elist, const float* __restrict__ dinv,
                   const float* __restrict__ prev, const float* __restrict__ bias,
                   float* __restrict__ outp) {
  int node = blockIdx.x, c = threadIdx.x;
  int s = noff[node], t = noff[node + 1];
  __shared__ int eds[64];
  float sum = 0.0f;
  for (int base = s; base < t; base += 64) {
    int nchunk = t - base; if (nchunk > 64) nchunk = 64;
    if (c < nchunk) eds[c] = elist[base + c];
    __syncthreads();
    for (int k = 0; k < nchunk; ++k)
      sum += e[(size_t)eds[k] * H_DIM + c];
    __syncthreads();
  }
  outp[(size_t)node * H_DIM + c] =
      prev[(size_t)node * H_DIM + c] + bias[c] + dinv[node] * sum;
}

// ------------------------------------------------------------------
// Transpose + f16 hi/lo split: src [Mp][Np] f32 -> hiT/loT [Np][Mp] f16.
__global__ __launch_bounds__(256)
void k_tsplit(const float* __restrict__ src, f16* __restrict__ hiT,
              f16* __restrict__ loT, int Mp, int Np, int withLo) {
  __shared__ float tile[64][65];
  int m0 = blockIdx.x * 64, n0 = blockIdx.y * 64;
  int tid = threadIdx.x;
#pragma unroll
  for (int i = 0; i < 4; ++i) {
    int q = tid + 256 * i;             // 1024 float4 = 64 rows x 64 cols
    int row = q >> 4, c4 = (q & 15) << 2;
    float4 v = *reinterpret_cast<const float4*>(&src[(size_t)(m0 + row) * Np + n0 + c4]);
    tile[row][c4] = v.x; tile[row][c4 + 1] = v.y;
    tile[row][c4 + 2] = v.z; tile[row][c4 + 3] = v.w;
  }
  __syncthreads();
#pragma unroll
  for (int i = 0; i < 4; ++i) {
    int q = tid + 256 * i;
    int nrow = q >> 4, mc = (q & 15) << 2;
    f16x4 h, l;
#pragma unroll
    for (int j = 0; j < 4; ++j) {
      float v = tile[mc + j][nrow];
      h[j] = (f16)v;
      l[j] = (f16)(v - (float)h[j]);
    }
    *reinterpret_cast<f16x4*>(&hiT[(size_t)(n0 + nrow) * Mp + m0 + mc]) = h;
    if (withLo)
      *reinterpret_cast<f16x4*>(&loT[(size_t)(n0 + nrow) * Mp + m0 + mc]) = l;
  }
}

// ------------------------------------------------------------------
// One GRU time step, fused input+recurrent GEMM + cell epilogue.
__global__ __launch_bounds__(256)
void k_gru_step(const float* __restrict__ x, const float* __restrict__ hprev,
                float* __restrict__ hnext, float* __restrict__ last,
                const f16* __restrict__ wih, const f16* __restrict__ whh,
                const float* __restrict__ bih, const float* __restrict__ bhh,
                const int* __restrict__ order, const int* __restrict__ len_s,
                const int* __restrict__ Mts, int t) {
  int Mt = Mts[t];
  int m0 = blockIdx.y * 64;
  if (m0 >= Mt) return;
  int j0 = blockIdx.x * 64;
  __shared__ f16 Ax[64 * LSTR], Ahh[64 * LSTR], Ahl[64 * LSTR];
  __shared__ f16 Bw[6][64 * LSTR];   // 0..2: W_ih r,z,n  3..5: W_hh r,z,n
  __shared__ int sOrd[64], sLen[64];
  int tid = threadIdx.x;
  if (tid < 64) {
    int g = m0 + tid; if (g > Mt - 1) g = Mt - 1;
    sOrd[tid] = order[g]; sLen[tid] = len_s[g];
  }
  __syncthreads();

  int lane = tid & 63, wid = tid >> 6;
  int quad = lane >> 4, mr = lane & 15;
  f32x4 accR[4] = {}, accZ[4] = {}, accXN[4] = {}, accHN[4] = {};

  for (int kt = 0; kt < 8; ++kt) {
    int k0 = kt * 32;
#pragma unroll
    for (int i = 0; i < 2; ++i) {
      int q = tid + 256 * i;            // 512 float4: 64 rows x 8 f4
      int row = q >> 3, kc = (q & 7) << 2;
      int rclamp = m0 + row; if (rclamp > Mt - 1) rclamp = Mt - 1;
      const float4 vx = *reinterpret_cast<const float4*>(
          &x[(size_t)sOrd[row] * (T_STEPS * H_DIM) + (size_t)t * H_DIM + k0 + kc]);
      f16x4 hx;
      hx[0] = (f16)vx.x; hx[1] = (f16)vx.y; hx[2] = (f16)vx.z; hx[3] = (f16)vx.w;
      *reinterpret_cast<f16x4*>(&Ax[row * LSTR + kc]) = hx;
      const float4 vh = *reinterpret_cast<const float4*>(
          &hprev[(size_t)rclamp * H_DIM + k0 + kc]);
      f16 h0_ = (f16)vh.x, h1_ = (f16)vh.y, h2_ = (f16)vh.z, h3_ = (f16)vh.w;
      f16x4 hh, hl;
      hh[0] = h0_; hh[1] = h1_; hh[2] = h2_; hh[3] = h3_;
      hl[0] = (f16)(vh.x - (float)h0_); hl[1] = (f16)(vh.y - (float)h1_);
      hl[2] = (f16)(vh.z - (float)h2_); hl[3] = (f16)(vh.w - (float)h3_);
      *reinterpret_cast<f16x4*>(&Ahh[row * LSTR + kc]) = hh;
      *reinterpret_cast<f16x4*>(&Ahl[row * LSTR + kc]) = hl;
    }
#pragma unroll
    for (int i = 0; i < 6; ++i) {
      int c = tid + 256 * i;            // 1536 chunks of 8 f16
      int mat = c >> 8, cc = c & 255;
      int row = cc >> 2, kc = (cc & 3) << 3;
      const f16* src = (mat < 3) ? wih : whh;
      int gate = (mat < 3) ? mat : mat - 3;
      f16x8 v = *reinterpret_cast<const f16x8*>(
          &src[(size_t)(gate * 256 + j0 + row) * 256 + k0 + kc]);
      st8lds(&Bw[mat][row * LSTR + kc], v);
    }
    __syncthreads();
    f16x8 bfr[6];
#pragma unroll
    for (int mmt = 0; mmt < 6; ++mmt)
      bfr[mmt] = ld8lds(&Bw[mmt][(wid * 16 + mr) * LSTR + quad * 8]);
#pragma unroll
    for (int im = 0; im < 4; ++im) {
      f16x8 ax = ld8lds(&Ax[(im * 16 + mr) * LSTR + quad * 8]);
      f16x8 ah = ld8lds(&Ahh[(im * 16 + mr) * LSTR + quad * 8]);
      f16x8 al = ld8lds(&Ahl[(im * 16 + mr) * LSTR + quad * 8]);
      accR[im]  = __builtin_amdgcn_mfma_f32_16x16x32_f16(ax, bfr[0], accR[im], 0, 0, 0);
      accR[im]  = __builtin_amdgcn_mfma_f32_16x16x32_f16(ah, bfr[3], accR[im], 0, 0, 0);
      accR[im]  = __builtin_amdgcn_mfma_f32_16x16x32_f16(al, bfr[3], accR[im], 0, 0, 0);
      accZ[im]  = __builtin_amdgcn_mfma_f32_16x16x32_f16(ax, bfr[1], accZ[im], 0, 0, 0);
      accZ[im]  = __builtin_amdgcn_mfma_f32_16x16x32_f16(ah, bfr[4], accZ[im], 0, 0, 0);
      accZ[im]  = __builtin_amdgcn_mfma_f32_16x16x32_f16(al, bfr[4], accZ[im], 0, 0, 0);
      accXN[im] = __builtin_amdgcn_mfma_f32_16x16x32_f16(ax, bfr[2], accXN[im], 0, 0, 0);
      accHN[im] = __builtin_amdgcn_mfma_f32_16x16x32_f16(ah, bfr[5], accHN[im], 0, 0, 0);
      accHN[im] = __builtin_amdgcn_mfma_f32_16x16x32_f16(al, bfr[5], accHN[im], 0, 0, 0);
    }
    __syncthreads();
  }
  // epilogue: GRU cell. C/D layout: col=lane&15 (j), row=quad*4+reg (m).
  int j = j0 + wid * 16 + mr;
  float bir = bih[j], biz = bih[256 + j], bin_ = bih[512 + j];
  float bhr = bhh[j], bhz = bhh[256 + j], bhn = bhh[512 + j];
#pragma unroll
  for (int im = 0; im < 4; ++im) {
#pragma unroll
    for (int r = 0; r < 4; ++r) {
      int mloc = im * 16 + quad * 4 + r;
      int m = m0 + mloc;
      if (m < Mt) {
        float rg = 1.0f / (1.0f + expf(-(accR[im][r] + bir + bhr)));
        float zg = 1.0f / (1.0f + expf(-(accZ[im][r] + biz + bhz)));
        float ng = tanhf(accXN[im][r] + bin_ + rg * (accHN[im][r] + bhn));
        float hp = hprev[(size_t)m * H_DIM + j];
        float hv = (1.0f - zg) * ng + zg * hp;
        hnext[(size_t)m * H_DIM + j] = hv;
        if (t == sLen[mloc] - 1)
          last[(size_t)sOrd[mloc] * H_DIM + j] = hv;
      }
    }
  }
}

// ------------------------------------------------------------------
// 128x128 f16 MFMA GEMM, B always pre-split f16 [N,K] (B0=hi, B1=lo).
// AMODE 0: A f32 [M,K], on-the-fly hi/lo split.
// AMODE 1: A = bitmask (u32 words, K/32 per row) -> 0/1 f16.
// AMODE 2: A pre-split f16 [M,K] hi/lo (Ahi/Alo).
// NTERMS: 1 = Ah*Bh; 2 = +Al*Bh; 3 = +Ah*Bl.
// EPI: 0 store C f32; 1 threshold->bitmask (ballot); 2 store C*scale_m[m];
//      3 atomicAdd C += v*scale_m[m].
// SYMM (EPI=1): grid is triangular (skip by>bx); off-diag blocks also write
// the transposed bitmask chunk via ballot-transpose.
template<int AMODE, int NTERMS, int EPI, int SYMM>
__global__ __launch_bounds__(256)
void k_gemm(const float* __restrict__ A, const f16* __restrict__ Ahi,
            const f16* __restrict__ Alo, const u32* __restrict__ Abits,
            const f16* __restrict__ B0, const f16* __restrict__ B1,
            float* __restrict__ C, u16* __restrict__ bitsOut,
            const float* __restrict__ scale_m, const float* __restrict__ phi_p,
            int M, int Nn, int K, int kLen) {
  int bx = blockIdx.x, by = blockIdx.y;
  if (SYMM && by > bx) return;
  int n0 = bx * 128, m0 = by * 128;
  int kStart = blockIdx.z * kLen;
  constexpr int SB = 128 * LSTR;
  constexpr int NBUF = (NTERMS == 3) ? 4 : ((NTERMS == 2) ? 3 : 2);
  __shared__ f16 smem[SB * NBUF];
  f16* Ah = smem;
  f16* Bh = smem + SB;
  f16* Al = smem + 2 * SB;   // valid iff NTERMS>=2
  f16* Bl = smem + 3 * SB;   // valid iff NTERMS==3
  int tid = threadIdx.x;
  int lane = tid & 63, wid = tid >> 6;
  int wm = wid & 1, wn = wid >> 1;
  int quad = lane >> 4, mr = lane & 15;
  f32x4 acc[4][4] = {};
  const int nkt = kLen >> 5;
  for (int kt = 0; kt < nkt; ++kt) {
    int kg = kStart + (kt << 5);
    if (AMODE == 0) {
#pragma unroll
      for (int i = 0; i < 4; ++i) {
        int q = tid + 256 * i;          // 1024 float4: 128 rows x 8
        int row = q >> 3, kc = (q & 7) << 2;
        float4 v = *reinterpret_cast<const float4*>(&A[(size_t)(m0 + row) * K + kg + kc]);
        f16 h0_ = (f16)v.x, h1_ = (f16)v.y, h2_ = (f16)v.z, h3_ = (f16)v.w;
        f16x4 hh; hh[0] = h0_; hh[1] = h1_; hh[2] = h2_; hh[3] = h3_;
        *reinterpret_cast<f16x4*>(&Ah[row * LSTR + kc]) = hh;
        if (NTERMS >= 2) {
          f16x4 hl;
          hl[0] = (f16)(v.x - (float)h0_); hl[1] = (f16)(v.y - (float)h1_);
          hl[2] = (f16)(v.z - (float)h2_); hl[3] = (f16)(v.w - (float)h3_);
          *reinterpret_cast<f16x4*>(&Al[row * LSTR + kc]) = hl;
        }
      }
    } else if (AMODE == 2) {
#pragma unroll
      for (int i = 0; i < 2; ++i) {
        int c = tid + 256 * i;          // 512 chunks of 8 f16
        int row = c >> 2, kc = (c & 3) << 3;
        f16x8 v = *reinterpret_cast<const f16x8*>(&Ahi[(size_t)(m0 + row) * K + kg + kc]);
        st8lds(&Ah[row * LSTR + kc], v);
        if (NTERMS >= 2) {
          f16x8 v2 = *reinterpret_cast<const f16x8*>(&Alo[(size_t)(m0 + row) * K + kg + kc]);
          st8lds(&Al[row * LSTR + kc], v2);
        }
      }
    } else {
      if (tid < 128) {
        int row = tid;
        u32 w = Abits[(size_t)(m0 + row) * (K >> 5) + (kg >> 5)];
        u32* dst = reinterpret_cast<u32*>(&Ah[row * LSTR]);
#pragma unroll
        for (int p = 0; p < 16; ++p) {
          union { f16 h[2]; u32 u; } pk;
          pk.h[0] = ((w >> (2 * p)) & 1u) ? (f16)1.0f : (f16)0.0f;
          pk.h[1] = ((w >> (2 * p + 1)) & 1u) ? (f16)1.0f : (f16)0.0f;
          dst[p] = pk.u;
        }
      }
    }
    // B stage: pre-split f16 [N,K]
#pragma unroll
    for (int i = 0; i < 2; ++i) {
      int c = tid + 256 * i;            // 512 chunks of 8 f16
      int row = c >> 2, kc = (c & 3) << 3;
      f16x8 v = *reinterpret_cast<const f16x8*>(&B0[(size_t)(n0 + row) * K + kg + kc]);
      st8lds(&Bh[row * LSTR + kc], v);
      if (NTERMS == 3) {
        f16x8 v2 = *reinterpret_cast<const f16x8*>(&B1[(size_t)(n0 + row) * K + kg + kc]);
        st8lds(&Bl[row * LSTR + kc], v2);
      }
    }
    __syncthreads();
    f16x8 af[4], bf[4], alr[4], blr[4];
#pragma unroll
    for (int im = 0; im < 4; ++im) {
      af[im] = ld8lds(&Ah[(wm * 64 + im * 16 + mr) * LSTR + quad * 8]);
      if (NTERMS >= 2)
        alr[im] = ld8lds(&Al[(wm * 64 + im * 16 + mr) * LSTR + quad * 8]);
    }
#pragma unroll
    for (int in = 0; in < 4; ++in) {
      bf[in] = ld8lds(&Bh[(wn * 64 + in * 16 + mr) * LSTR + quad * 8]);
      if (NTERMS == 3)
        blr[in] = ld8lds(&Bl[(wn * 64 + in * 16 + mr) * LSTR + quad * 8]);
    }
#pragma unroll
    for (int im = 0; im < 4; ++im)
#pragma unroll
      for (int in = 0; in < 4; ++in) {
        acc[im][in] = __builtin_amdgcn_mfma_f32_16x16x32_f16(af[im], bf[in], acc[im][in], 0, 0, 0);
        if (NTERMS >= 2)
          acc[im][in] = __builtin_amdgcn_mfma_f32_16x16x32_f16(alr[im], bf[in], acc[im][in], 0, 0, 0);
        if (NTERMS == 3)
          acc[im][in] = __builtin_amdgcn_mfma_f32_16x16x32_f16(af[im], blr[in], acc[im][in], 0, 0, 0);
      }
    __syncthreads();
  }
  float phiK = 0.0f;
  if (EPI == 1) phiK = phi_p[0] * 65536.0f;   // dot/65536 >= phi  <=>  dot >= phi*65536 (exact, pow2)
#pragma unroll
  for (int im = 0; im < 4; ++im) {
#pragma unroll
    for (int in = 0; in < 4; ++in) {
      int nn = n0 + wn * 64 + in * 16 + mr;
      int mb = m0 + wm * 64 + im * 16 + quad * 4;
      if (EPI == 1) {
        u64 bal[4];
#pragma unroll
        for (int r = 0; r < 4; ++r) {
          int m = mb + r;
          bool one = (acc[im][in][r] >= phiK) || (m == nn);   // diag forced to 1
          bal[r] = __ballot(one);
        }
#pragma unroll
        for (int r = 0; r < 4; ++r) {
          if (mr == 0) {
            u16 chunk = (u16)((bal[r] >> (16 * quad)) & 0xFFFFu);
            bitsOut[(size_t)(mb + r) * (Nn >> 4) + (nn >> 4)] = chunk;
          }
        }
        if (SYMM && m0 != n0) {
          // transposed chunk: row nn (by mr), 16 m-bits j=quad'*4+r'
          u32 tb = 0;
#pragma unroll
          for (int jb = 0; jb < 16; ++jb)
            tb |= (u32)((bal[jb & 3] >> ((jb >> 2) * 16 + mr)) & 1ull) << jb;
          if (quad == 0) {
            int nnr = n0 + wn * 64 + in * 16 + mr;
            int mch = (m0 + wm * 64 + im * 16) >> 4;
            bitsOut[(size_t)nnr * (Nn >> 4) + mch] = (u16)tb;
          }
        }
      } else {
#pragma unroll
        for (int r = 0; r < 4; ++r) {
          int m = mb + r;
          float v = acc[im][in][r];
          if (EPI == 0) {
            C[(size_t)m * Nn + nn] = v;
          } else if (EPI == 2) {
            C[(size_t)m * Nn + nn] = v * scale_m[m];
          } else {
            atomicAdd(&C[(size_t)m * Nn + nn], v * scale_m[m]);
          }
        }
      }
    }
  }
}

// ------------------------------------------------------------------
__global__ void k_split16(const float* __restrict__ src, f16* __restrict__ hi,
                          f16* __restrict__ lo) {
  int i = blockIdx.x * 256 + threadIdx.x;   // N*H
  float v = src[i];
  f16 h = (f16)v;
  hi[i] = h; lo[i] = (f16)(v - (float)h);
}

__global__ void k_degdis(const u32* __restrict__ bits, float* __restrict__ dis) {
  __shared__ int red[4];
  int row = blockIdx.x, tid = threadIdx.x;
  u32 w = bits[(size_t)row * 256 + tid];
  int c = __popc(w);
  for (int off = 32; off > 0; off >>= 1) c += __shfl_down(c, off);
  if ((tid & 63) == 0) red[tid >> 6] = c;
  __syncthreads();
  if (tid == 0) {
    int s = red[0] + red[1] + red[2] + red[3];
    dis[row] = s > 0 ? rsqrtf((float)s) : 0.0f;
  }
}

__global__ void k_outinit(const float* __restrict__ b, float* __restrict__ out) {
  int i = blockIdx.x * 256 + threadIdx.x;
  out[i] = b[i & (H_DIM - 1)];
}

// ------------------------------------------------------------------
extern "C" void kernel_launch(void* const* d_in, const int* in_sizes, int n_in,
                              void* d_out, int out_size, void* d_ws, size_t ws_size,
                              hipStream_t stream) {
  (void)in_sizes; (void)n_in; (void)out_size; (void)ws_size;
  const float* x    = (const float*)d_in[0];
  const int*   he   = (const int*)d_in[1];
  const int*   slen = (const int*)d_in[2];
  const float* h0   = (const float*)d_in[3];
  const float* wih  = (const float*)d_in[4];
  const float* whh  = (const float*)d_in[5];
  const float* bih  = (const float*)d_in[6];
  const float* bhh  = (const float*)d_in[7];
  const float* hw[3] = {(const float*)d_in[8], (const float*)d_in[10], (const float*)d_in[12]};
  const float* hb[3] = {(const float*)d_in[9], (const float*)d_in[11], (const float*)d_in[13]};
  const float* phi  = (const float*)d_in[14];
  const float* gw   = (const float*)d_in[15];
  const float* gb   = (const float*)d_in[16];
  float* out = (float*)d_out;

  // ---- workspace layout (~70 MB), everything re-initialized every call ----
  size_t off = 0;
  char* wsb = (char*)d_ws;
  auto alloc = [&](size_t b) { void* p = wsb + off; off += (b + 255) & ~(size_t)255; return p; };
  int*   order = (int*)alloc(N_NODES * 4);
  int*   lens  = (int*)alloc(N_NODES * 4);
  int*   Mts   = (int*)alloc(256);
  u32*   histD = (u32*)alloc(N_NODES * 4);
  u32*   histB = (u32*)alloc(N_EDGES * 4);
  float* dinv  = (float*)alloc(N_NODES * 4);
  float* binv  = (float*)alloc(N_EDGES * 4);
  float* dis   = (float*)alloc(N_NODES * 4);
  int*   noff  = (int*)alloc((N_NODES + 1) * 4);
  int*   eoff  = (int*)alloc((N_EDGES + 1) * 4);
  int*   ncur  = (int*)alloc(N_NODES * 4);
  int*   ecur  = (int*)alloc(N_EDGES * 4);
  int*   nlist = (int*)alloc(NNZ_ * 4);
  int*   elist = (int*)alloc(NNZ_ * 4);
  f16*   wih16 = (f16*)alloc(768 * 256 * 2);
  f16*   whh16 = (f16*)alloc(768 * 256 * 2);
  f16*   hwT[3]; f16* hwTlo[3];
  for (int c = 0; c < 3; ++c) {
    hwT[c]   = (f16*)alloc(256 * 256 * 2);
    hwTlo[c] = (f16*)alloc(256 * 256 * 2);
  }
  f16*   gwT   = (f16*)alloc(256 * 256 * 2);
  f16*   gwTlo = (f16*)alloc(256 * 256 * 2);
  float* ha    = (float*)alloc((size_t)N_NODES * H_DIM * 4);
  float* hb2   = (float*)alloc((size_t)N_NODES * H_DIM * 4);
  float* oA    = (float*)alloc((size_t)N_NODES * H_DIM * 4);   // `last`, then o2
  float* oB    = (float*)alloc((size_t)N_NODES * H_DIM * 4);   // o1, then o3
  float* xwb   = (float*)alloc((size_t)N_NODES * H_DIM * 4);   // xw scratch / z
  float* eb    = (float*)alloc((size_t)N_EDGES * H_DIM * 4);
  f16*   o3hi  = (f16*)alloc((size_t)N_NODES * H_DIM * 2);
  f16*   o3lo  = (f16*)alloc((size_t)N_NODES * H_DIM * 2);
  f16*   z16T  = (f16*)alloc((size_t)H_DIM * N_NODES * 2);     // z^T [256][8192]
  u32*   Abits = (u32*)alloc((size_t)N_NODES * 256 * 4);       // 8192x8192 bits

  // ---- preprocessing ----
  k_sort<<<1, 256, 0, stream>>>(slen, order, lens, Mts);
  k_w16<<<768, 256, 0, stream>>>(wih, whh, wih16, whh16);
  k_hinit<<<N_NODES, 256, 0, stream>>>(h0, ha);
  hipMemsetAsync(histD, 0, N_NODES * 4, stream);
  hipMemsetAsync(histB, 0, N_EDGES * 4, stream);
  k_hist<<<NNZ_ / 256, 256, 0, stream>>>(he, histD, histB);
  k_inv<<<N_NODES / 256, 256, 0, stream>>>(histD, histB, dinv, binv);
  k_scan<<<1, 256, 0, stream>>>(histD, histB, noff, eoff, ncur, ecur);
  k_fill<<<NNZ_ / 256, 256, 0, stream>>>(he, ncur, ecur, nlist, elist);
  for (int c = 0; c < 3; ++c)
    k_tsplit<<<dim3(4, 4), 256, 0, stream>>>(hw[c], hwT[c], hwTlo[c], 256, 256, 1);
  k_tsplit<<<dim3(4, 4), 256, 0, stream>>>(gw, gwT, gwTlo, 256, 256, 1);

  // ---- GRU: 32 fused steps, length-sorted with device-side early exit ----
  float* hcur = ha; float* hnxt = hb2;
  for (int t = 0; t < T_STEPS; ++t) {
    k_gru_step<<<dim3(4, 128), 256, 0, stream>>>(x, hcur, hnxt, oA, wih16, whh16,
                                                 bih, bhh, order, lens, Mts, t);
    float* tmp = hcur; hcur = hnxt; hnxt = tmp;
  }
  // oA now holds `last` in original node order.

  // ---- 3x HypergraphConv with residual (CSR gather, no atomics) ----
  float* prev = oA; float* nxt = oB;
  for (int c = 0; c < 3; ++c) {
    k_gemm<0, 3, 0, 0><<<dim3(2, 64, 1), 256, 0, stream>>>(
        prev, nullptr, nullptr, nullptr, hwT[c], hwTlo[c], xwb, nullptr,
        nullptr, nullptr, N_NODES, H_DIM, H_DIM, H_DIM);
    k_edge_gather<<<N_EDGES, 256, 0, stream>>>(xwb, eoff, nlist, binv, eb);
    k_node_gather<<<N_NODES, 256, 0, stream>>>(eb, noff, elist, dinv, prev, hb[c], nxt);
    float* tmp = prev; prev = nxt; nxt = tmp;
  }
  float* o3 = prev;  // == oB after 3 swaps

  // ---- dynamic adjacency: gram -> bitmask (triangular + mirrored), degrees ----
  k_split16<<<N_NODES, 256, 0, stream>>>(o3, o3hi, o3lo);
  k_gemm<2, 3, 1, 1><<<dim3(64, 64, 1), 256, 0, stream>>>(
      nullptr, o3hi, o3lo, nullptr, o3hi, o3lo, nullptr, (u16*)Abits,
      nullptr, phi, N_NODES, N_NODES, H_DIM, H_DIM);
  k_degdis<<<N_NODES, 256, 0, stream>>>(Abits, dis);

  // ---- z = dis .* (o3 @ gcn_w), then transpose-split to z16T ----
  k_gemm<2, 3, 2, 0><<<dim3(2, 64, 1), 256, 0, stream>>>(
      nullptr, o3hi, o3lo, nullptr, gwT, gwTlo, xwb, nullptr,
      dis, nullptr, N_NODES, H_DIM, H_DIM, H_DIM);
  k_tsplit<<<dim3(128, 4), 256, 0, stream>>>(xwb, z16T, nullptr, N_NODES, H_DIM, 0);

  // ---- out = dis .* (A @ z) + gcn_b  (bitmask A in LDS, split-K=4) ----
  k_outinit<<<N_NODES, 256, 0, stream>>>(gb, out);
  k_gemm<1, 1, 3, 0><<<dim3(2, 64, 4), 256, 0, stream>>>(
      nullptr, nullptr, nullptr, Abits, z16T, nullptr, out, nullptr,
      dis, nullptr, N_NODES, H_DIM, N_NODES, N_NODES / 4);
}